// Round 1
// baseline (1399.710 us; speedup 1.0000x reference)
//
#include <hip/hip_runtime.h>

#define BM 128
#define BN 128
#define BK 16

// ---------------- graph preprocessing ----------------

__global__ void count_deg(const int* __restrict__ dst, int* __restrict__ cnt, int E) {
    int i = blockIdx.x * blockDim.x + threadIdx.x;
    if (i < E) atomicAdd(&cnt[dst[i]], 1);
}

__global__ __launch_bounds__(1024) void scan_kernel(const int* __restrict__ cnt,
                                                    int* __restrict__ row_ptr,
                                                    float* __restrict__ inv_s,
                                                    int n, int Etot) {
    __shared__ int sums[1024];
    int tid = threadIdx.x;
    int chunk = (n + 1023) / 1024;
    int start = tid * chunk;
    int end = start + chunk; if (end > n) end = n;
    int s = 0;
    for (int i = start; i < end; ++i) s += cnt[i];
    sums[tid] = s;
    __syncthreads();
    for (int off = 1; off < 1024; off <<= 1) {
        int v = (tid >= off) ? sums[tid - off] : 0;
        __syncthreads();
        sums[tid] += v;
        __syncthreads();
    }
    int base = (tid == 0) ? 0 : sums[tid - 1];
    for (int i = start; i < end; ++i) {
        row_ptr[i] = base;
        int c = cnt[i];
        inv_s[i] = rsqrtf((float)(c + 1));   // +1 self loop; deg>=1 always
        base += c;
    }
    if (tid == 0) row_ptr[n] = Etot;
}

__global__ void fill_csr(const int* __restrict__ src, const int* __restrict__ dst,
                         const int* __restrict__ row_ptr, int* __restrict__ fill_cnt,
                         int* __restrict__ col_idx, int E) {
    int i = blockIdx.x * blockDim.x + threadIdx.x;
    if (i < E) {
        int d = dst[i];
        int pos = row_ptr[d] + atomicAdd(&fill_cnt[d], 1);
        col_idx[pos] = src[i];
    }
}

// ---------------- dense f32 GEMM: C[M,256] = A[M,256] @ B[256,256] ----------------

__global__ __launch_bounds__(256) void gemm_f32(const float* __restrict__ A,
                                                const float* __restrict__ B,
                                                float* __restrict__ C,
                                                int M, int K, int Ncol) {
    __shared__ float As[BK][BM + 4];
    __shared__ float Bs[BK][BN + 4];
    int tid = threadIdx.x;
    int row0 = blockIdx.x * BM;
    int col0 = blockIdx.y * BN;
    int tx = tid & 15, ty = tid >> 4;
    float acc[8][8] = {};

    for (int k0 = 0; k0 < K; k0 += BK) {
        #pragma unroll
        for (int i = 0; i < 2; ++i) {
            int q = tid + i * 256;
            int ar = q >> 2, ac = (q & 3) << 2;
            int grow = row0 + ar;
            float4 v = make_float4(0.f, 0.f, 0.f, 0.f);
            if (grow < M) v = *(const float4*)(A + (size_t)grow * K + k0 + ac);
            As[ac + 0][ar] = v.x;
            As[ac + 1][ar] = v.y;
            As[ac + 2][ar] = v.z;
            As[ac + 3][ar] = v.w;
        }
        #pragma unroll
        for (int i = 0; i < 2; ++i) {
            int q = tid + i * 256;
            int br = q >> 5, bc = (q & 31) << 2;
            float4 v = *(const float4*)(B + (size_t)(k0 + br) * Ncol + col0 + bc);
            *(float4*)&Bs[br][bc] = v;
        }
        __syncthreads();
        #pragma unroll
        for (int kk = 0; kk < BK; ++kk) {
            float4 a0 = *(const float4*)&As[kk][ty * 8];
            float4 a1 = *(const float4*)&As[kk][ty * 8 + 4];
            float4 b0 = *(const float4*)&Bs[kk][tx * 8];
            float4 b1 = *(const float4*)&Bs[kk][tx * 8 + 4];
            float a[8] = {a0.x, a0.y, a0.z, a0.w, a1.x, a1.y, a1.z, a1.w};
            float b[8] = {b0.x, b0.y, b0.z, b0.w, b1.x, b1.y, b1.z, b1.w};
            #pragma unroll
            for (int i = 0; i < 8; ++i)
                #pragma unroll
                for (int j = 0; j < 8; ++j)
                    acc[i][j] = fmaf(a[i], b[j], acc[i][j]);
        }
        __syncthreads();
    }
    #pragma unroll
    for (int i = 0; i < 8; ++i) {
        int grow = row0 + ty * 8 + i;
        if (grow < M) {
            float4 o0 = make_float4(acc[i][0], acc[i][1], acc[i][2], acc[i][3]);
            float4 o1 = make_float4(acc[i][4], acc[i][5], acc[i][6], acc[i][7]);
            *(float4*)(C + (size_t)grow * Ncol + col0 + tx * 8) = o0;
            *(float4*)(C + (size_t)grow * Ncol + col0 + tx * 8 + 4) = o1;
        }
    }
}

// ---------------- GCN aggregation (wave per node) ----------------
// out[i] = relu?( inv_s[i]*( inv_s[i]*h[i] + sum_{e:dst=i} inv_s[src]*h[src] ) + b )

__global__ __launch_bounds__(256) void aggregate(const float* __restrict__ h,
                                                 const int* __restrict__ row_ptr,
                                                 const int* __restrict__ col_idx,
                                                 const float* __restrict__ inv_s,
                                                 const float* __restrict__ bias,
                                                 float* __restrict__ out,
                                                 int n, int do_relu) {
    int wave = threadIdx.x >> 6;
    int lane = threadIdx.x & 63;
    int node = blockIdx.x * 4 + wave;
    if (node >= n) return;
    float s_i = inv_s[node];
    float4 acc = *(const float4*)(h + (size_t)node * 256 + lane * 4);
    acc.x *= s_i; acc.y *= s_i; acc.z *= s_i; acc.w *= s_i;
    int e0 = row_ptr[node], e1 = row_ptr[node + 1];
    for (int e = e0; e < e1; ++e) {
        int src = col_idx[e];
        float s = inv_s[src];
        float4 v = *(const float4*)(h + (size_t)src * 256 + lane * 4);
        acc.x = fmaf(s, v.x, acc.x);
        acc.y = fmaf(s, v.y, acc.y);
        acc.z = fmaf(s, v.z, acc.z);
        acc.w = fmaf(s, v.w, acc.w);
    }
    float4 b = *(const float4*)(bias + lane * 4);
    float4 o;
    o.x = fmaf(s_i, acc.x, b.x);
    o.y = fmaf(s_i, acc.y, b.y);
    o.z = fmaf(s_i, acc.z, b.z);
    o.w = fmaf(s_i, acc.w, b.w);
    if (do_relu) {
        o.x = fmaxf(o.x, 0.f); o.y = fmaxf(o.y, 0.f);
        o.z = fmaxf(o.z, 0.f); o.w = fmaxf(o.w, 0.f);
    }
    *(float4*)(out + (size_t)node * 256 + lane * 4) = o;
}

// ---------------- context GEMM fused with gather + mask + final product ----------
// out[i,:] = feat[i,:] * ( sum_{j<len_i} feat[label[i,j],:] @ rW[j*256:(j+1)*256,:] + rb )

__global__ __launch_bounds__(256) void ctx_gemm(const float* __restrict__ feat,
                                                const int* __restrict__ label,
                                                const int* __restrict__ clen,
                                                const float* __restrict__ rW,
                                                const float* __restrict__ rb,
                                                float* __restrict__ out, int M) {
    __shared__ float As[BK][BM + 4];
    __shared__ float Bs[BK][BN + 4];
    __shared__ int s_lbl[BM];
    __shared__ int s_len[BM];
    __shared__ int s_max;
    int tid = threadIdx.x;
    int row0 = blockIdx.x * BM;
    int col0 = blockIdx.y * BN;
    int tx = tid & 15, ty = tid >> 4;

    if (tid < BM) {
        int r = row0 + tid;
        s_len[tid] = (r < M) ? clen[r] : 0;
    }
    if (tid == 0) s_max = 0;
    __syncthreads();
    if (tid < BM) atomicMax(&s_max, s_len[tid]);
    __syncthreads();
    int maxlen = s_max;   // <= 7 always (len < 8)

    float acc[8][8] = {};
    for (int j = 0; j < maxlen; ++j) {
        if (tid < BM) {
            int r = row0 + tid;
            int ok = (r < M) && (j < s_len[tid]);
            s_lbl[tid] = ok ? label[(size_t)r * 8 + j] : -1;
        }
        __syncthreads();
        for (int k0 = 0; k0 < 256; k0 += BK) {
            #pragma unroll
            for (int i = 0; i < 2; ++i) {
                int q = tid + i * 256;
                int ar = q >> 2, ac = (q & 3) << 2;
                int lbl = s_lbl[ar];
                float4 v = make_float4(0.f, 0.f, 0.f, 0.f);
                if (lbl >= 0) v = *(const float4*)(feat + (size_t)lbl * 256 + k0 + ac);
                As[ac + 0][ar] = v.x;
                As[ac + 1][ar] = v.y;
                As[ac + 2][ar] = v.z;
                As[ac + 3][ar] = v.w;
            }
            #pragma unroll
            for (int i = 0; i < 2; ++i) {
                int q = tid + i * 256;
                int br = q >> 5, bc = (q & 31) << 2;
                float4 v = *(const float4*)(rW + (size_t)(j * 256 + k0 + br) * 256 + col0 + bc);
                *(float4*)&Bs[br][bc] = v;
            }
            __syncthreads();
            #pragma unroll
            for (int kk = 0; kk < BK; ++kk) {
                float4 a0 = *(const float4*)&As[kk][ty * 8];
                float4 a1 = *(const float4*)&As[kk][ty * 8 + 4];
                float4 b0 = *(const float4*)&Bs[kk][tx * 8];
                float4 b1 = *(const float4*)&Bs[kk][tx * 8 + 4];
                float a[8] = {a0.x, a0.y, a0.z, a0.w, a1.x, a1.y, a1.z, a1.w};
                float b[8] = {b0.x, b0.y, b0.z, b0.w, b1.x, b1.y, b1.z, b1.w};
                #pragma unroll
                for (int i = 0; i < 8; ++i)
                    #pragma unroll
                    for (int jj = 0; jj < 8; ++jj)
                        acc[i][jj] = fmaf(a[i], b[jj], acc[i][jj]);
            }
            __syncthreads();
        }
    }
    // epilogue: out = feat * (acc + rb)
    float4 rb0 = *(const float4*)(rb + col0 + tx * 8);
    float4 rb1 = *(const float4*)(rb + col0 + tx * 8 + 4);
    #pragma unroll
    for (int i = 0; i < 8; ++i) {
        int grow = row0 + ty * 8 + i;
        if (grow < M) {
            float4 f0 = *(const float4*)(feat + (size_t)grow * 256 + col0 + tx * 8);
            float4 f1 = *(const float4*)(feat + (size_t)grow * 256 + col0 + tx * 8 + 4);
            float4 o0, o1;
            o0.x = (acc[i][0] + rb0.x) * f0.x;
            o0.y = (acc[i][1] + rb0.y) * f0.y;
            o0.z = (acc[i][2] + rb0.z) * f0.z;
            o0.w = (acc[i][3] + rb0.w) * f0.w;
            o1.x = (acc[i][4] + rb1.x) * f1.x;
            o1.y = (acc[i][5] + rb1.y) * f1.y;
            o1.z = (acc[i][6] + rb1.z) * f1.z;
            o1.w = (acc[i][7] + rb1.w) * f1.w;
            *(float4*)(out + (size_t)grow * 256 + col0 + tx * 8) = o0;
            *(float4*)(out + (size_t)grow * 256 + col0 + tx * 8 + 4) = o1;
        }
    }
}

// ---------------- launch ----------------

extern "C" void kernel_launch(void* const* d_in, const int* in_sizes, int n_in,
                              void* d_out, int out_size, void* d_ws, size_t ws_size,
                              hipStream_t stream) {
    const float* x         = (const float*)d_in[0];
    const int*   edge_idx  = (const int*)d_in[1];
    const int*   node_lbl  = (const int*)d_in[2];
    const int*   ctx_len   = (const int*)d_in[3];
    const float* gcn_W     = (const float*)d_in[4];
    const float* gcn_b     = (const float*)d_in[5];
    const float* resize_W  = (const float*)d_in[6];
    const float* resize_b  = (const float*)d_in[7];

    const int N = in_sizes[3];
    const int E = in_sizes[1] / 2;
    const int H = 256;
    const int* esrc = edge_idx;
    const int* edst = edge_idx + E;

    char* ws = (char*)d_ws;
    size_t off = 0;
    auto take = [&](size_t bytes) -> char* {
        char* p = ws + off;
        off = (off + bytes + 255) & ~(size_t)255;
        return p;
    };
    int*   cnt      = (int*)take((size_t)2 * N * sizeof(int));   // cnt + fill_cnt
    int*   fill_cnt = cnt + N;
    int*   row_ptr  = (int*)take((size_t)(N + 1) * sizeof(int));
    int*   col_idx  = (int*)take((size_t)E * sizeof(int));
    float* inv_s    = (float*)take((size_t)N * sizeof(float));
    float* feat     = (float*)take((size_t)N * H * sizeof(float));
    float* bufA     = (float*)d_out;   // h1 / h2 scratch; overwritten by final output

    hipMemsetAsync(cnt, 0, (size_t)2 * N * sizeof(int), stream);
    count_deg<<<(E + 255) / 256, 256, 0, stream>>>(edst, cnt, E);
    scan_kernel<<<1, 1024, 0, stream>>>(cnt, row_ptr, inv_s, N, E);
    fill_csr<<<(E + 255) / 256, 256, 0, stream>>>(esrc, edst, row_ptr, fill_cnt, col_idx, E);

    dim3 ggrid((N + BM - 1) / BM, H / BN);
    // layer 1
    gemm_f32<<<ggrid, 256, 0, stream>>>(x, gcn_W, bufA, N, H, H);
    aggregate<<<(N + 3) / 4, 256, 0, stream>>>(bufA, row_ptr, col_idx, inv_s, gcn_b, feat, N, 1);
    // layer 2
    gemm_f32<<<ggrid, 256, 0, stream>>>(feat, gcn_W, bufA, N, H, H);
    aggregate<<<(N + 3) / 4, 256, 0, stream>>>(bufA, row_ptr, col_idx, inv_s, gcn_b, feat, N, 0);
    // context resize + final elementwise product
    ctx_gemm<<<ggrid, 256, 0, stream>>>(feat, node_lbl, ctx_len, resize_W, resize_b,
                                        (float*)d_out, N);
}

// Round 2
// 1349.933 us; speedup vs baseline: 1.0369x; 1.0369x over previous
//
#include <hip/hip_runtime.h>

typedef _Float16 f16;
typedef _Float16 f16x8 __attribute__((ext_vector_type(8)));
typedef float f32x16 __attribute__((ext_vector_type(16)));

#define BM 128
#define BN 128
#define BK 32

__device__ __forceinline__ void gload_lds16(const f16* g, f16* l) {
    __builtin_amdgcn_global_load_lds(
        (const __attribute__((address_space(1))) unsigned int*)g,
        (__attribute__((address_space(3))) unsigned int*)l, 16, 0, 0);
}

union H4 { f16 f[4]; ushort4 u; };

// ---------------- graph preprocessing ----------------

__global__ void count_deg(const int* __restrict__ dst, int* __restrict__ cnt, int E) {
    int i = blockIdx.x * blockDim.x + threadIdx.x;
    if (i < E) atomicAdd(&cnt[dst[i]], 1);
}

__global__ __launch_bounds__(1024) void scan_kernel(const int* __restrict__ cnt,
                                                    int* __restrict__ row_ptr,
                                                    float* __restrict__ inv_s,
                                                    int n, int Etot) {
    __shared__ int sums[1024];
    int tid = threadIdx.x;
    int chunk = (n + 1023) / 1024;
    int start = tid * chunk;
    int end = start + chunk; if (end > n) end = n;
    int s = 0;
    for (int i = start; i < end; ++i) s += cnt[i];
    sums[tid] = s;
    __syncthreads();
    for (int off = 1; off < 1024; off <<= 1) {
        int v = (tid >= off) ? sums[tid - off] : 0;
        __syncthreads();
        sums[tid] += v;
        __syncthreads();
    }
    int base = (tid == 0) ? 0 : sums[tid - 1];
    for (int i = start; i < end; ++i) {
        row_ptr[i] = base;
        int c = cnt[i];
        inv_s[i] = rsqrtf((float)(c + 1));
        base += c;
    }
    if (tid == 0) row_ptr[n] = Etot;
}

__global__ void fill_csr(const int* __restrict__ src, const int* __restrict__ dst,
                         const int* __restrict__ row_ptr, int* __restrict__ fill_cnt,
                         int* __restrict__ col_idx, int E) {
    int i = blockIdx.x * blockDim.x + threadIdx.x;
    if (i < E) {
        int d = dst[i];
        int pos = row_ptr[d] + atomicAdd(&fill_cnt[d], 1);
        col_idx[pos] = src[i];
    }
}

__global__ void hist_len(const int* __restrict__ clen, int* __restrict__ hist, int n) {
    int i = blockIdx.x * blockDim.x + threadIdx.x;
    if (i < n) { int l = clen[i]; if (l < 0) l = 0; if (l > 8) l = 8; atomicAdd(&hist[l], 1); }
}

__global__ void scan9(int* hist) {
    if (threadIdx.x == 0 && blockIdx.x == 0) {
        int run = 0;
        for (int i = 0; i < 9; ++i) { int c = hist[i]; hist[i] = run; run += c; }
    }
}

__global__ void scatter_perm(const int* __restrict__ clen, int* __restrict__ hist,
                             int* __restrict__ perm, int n) {
    int i = blockIdx.x * blockDim.x + threadIdx.x;
    if (i < n) {
        int l = clen[i]; if (l < 0) l = 0; if (l > 8) l = 8;
        int pos = atomicAdd(&hist[l], 1);
        perm[pos] = i;
    }
}

__global__ void ctx_len_fill(const int* __restrict__ clen, const int* __restrict__ perm,
                             int* __restrict__ plen, int n) {
    int i = blockIdx.x * blockDim.x + threadIdx.x;
    if (i < n) {
        int l = clen[perm[i]];
        if (l < 0) l = 0; if (l > 8) l = 8;
        plen[i] = l;
    }
}

// W[K][256] -> transposed split th/tl[256][K]
__global__ void split_wt(const float* __restrict__ W, f16* __restrict__ th,
                         f16* __restrict__ tl, int K) {
    int idx = blockIdx.x * blockDim.x + threadIdx.x;
    if (idx >= K * 256) return;
    int nrow = idx / K;
    int k = idx - nrow * K;
    float v = W[(size_t)k * 256 + nrow];
    f16 h = (f16)v; f16 l = (f16)(v - (float)h);
    th[idx] = h; tl[idx] = l;
}

// ---------------- aggregation (wave per node) ----------------

__global__ __launch_bounds__(256) void agg_f32(const float* __restrict__ x,
        const int* __restrict__ rp, const int* __restrict__ ci,
        const float* __restrict__ invs, f16* __restrict__ ohi, f16* __restrict__ olo, int n) {
    int wv = threadIdx.x >> 6, lane = threadIdx.x & 63;
    int node = blockIdx.x * 4 + wv; if (node >= n) return;
    float si = invs[node];
    float4 a = *(const float4*)(x + (size_t)node * 256 + lane * 4);
    float4 acc = make_float4(a.x * si, a.y * si, a.z * si, a.w * si);
    int e0 = rp[node], e1 = rp[node + 1];
    for (int e = e0; e < e1; ++e) {
        int s = ci[e];
        float ss = invs[s];
        float4 v = *(const float4*)(x + (size_t)s * 256 + lane * 4);
        acc.x = fmaf(ss, v.x, acc.x); acc.y = fmaf(ss, v.y, acc.y);
        acc.z = fmaf(ss, v.z, acc.z); acc.w = fmaf(ss, v.w, acc.w);
    }
    float o[4] = {si * acc.x, si * acc.y, si * acc.z, si * acc.w};
    H4 hh, ll;
    #pragma unroll
    for (int k = 0; k < 4; ++k) { f16 h = (f16)o[k]; hh.f[k] = h; ll.f[k] = (f16)(o[k] - (float)h); }
    size_t off = (size_t)node * 256 + lane * 4;
    *(ushort4*)(ohi + off) = hh.u;
    *(ushort4*)(olo + off) = ll.u;
}

__global__ __launch_bounds__(256) void agg_pair(const f16* __restrict__ xhi, const f16* __restrict__ xlo,
        const int* __restrict__ rp, const int* __restrict__ ci,
        const float* __restrict__ invs, f16* __restrict__ ohi, f16* __restrict__ olo, int n) {
    int wv = threadIdx.x >> 6, lane = threadIdx.x & 63;
    int node = blockIdx.x * 4 + wv; if (node >= n) return;
    float si = invs[node];
    size_t off = (size_t)node * 256 + lane * 4;
    H4 sh, sl; sh.u = *(const ushort4*)(xhi + off); sl.u = *(const ushort4*)(xlo + off);
    float acc[4];
    #pragma unroll
    for (int k = 0; k < 4; ++k) acc[k] = si * ((float)sh.f[k] + (float)sl.f[k]);
    int e0 = rp[node], e1 = rp[node + 1];
    for (int e = e0; e < e1; ++e) {
        int s = ci[e]; float ss = invs[s];
        size_t so = (size_t)s * 256 + lane * 4;
        H4 vh, vl; vh.u = *(const ushort4*)(xhi + so); vl.u = *(const ushort4*)(xlo + so);
        #pragma unroll
        for (int k = 0; k < 4; ++k) acc[k] = fmaf(ss, (float)vh.f[k] + (float)vl.f[k], acc[k]);
    }
    H4 hh, ll;
    #pragma unroll
    for (int k = 0; k < 4; ++k) {
        float v = si * acc[k];
        f16 h = (f16)v; hh.f[k] = h; ll.f[k] = (f16)(v - (float)h);
    }
    *(ushort4*)(ohi + off) = hh.u;
    *(ushort4*)(olo + off) = ll.u;
}

// ---------------- split-f16 MFMA GEMM ----------------

__global__ __launch_bounds__(256) void gemm_pair(
        const f16* __restrict__ Ahi, const f16* __restrict__ Alo,
        const f16* __restrict__ Bhi, const f16* __restrict__ Blo,
        const float* __restrict__ bias,
        f16* __restrict__ Ohi, f16* __restrict__ Olo,
        float* __restrict__ Of32,
        const f16* __restrict__ zp, int M, int relu) {
    __shared__ __align__(16) f16 LA[2][4096];
    __shared__ __align__(16) f16 LB[2][4096];
    int tid = threadIdx.x, w = tid >> 6, lane = tid & 63;
    int row0 = blockIdx.x * BM, col0 = blockIdx.y * BN;
    int wr = w >> 1, wc = w & 1;
    f32x16 acc[2][2] = {};

    const f16* g0; const f16* g1;
    f16* ldsbase = (w == 0) ? LA[0] : (w == 1) ? LA[1] : (w == 2) ? LB[0] : LB[1];
    if (w < 2) {
        const f16* s = (w == 0) ? Ahi : Alo;
        int r0v = row0 + lane, r1v = row0 + 64 + lane;
        g0 = (r0v < M) ? s + (size_t)r0v * 256 : zp;
        g1 = (r1v < M) ? s + (size_t)r1v * 256 : zp;
    } else {
        const f16* s = (w == 2) ? Bhi : Blo;
        g0 = s + (size_t)(col0 + lane) * 256;
        g1 = s + (size_t)(col0 + 64 + lane) * 256;
    }

    int kh = lane >> 5, lm = lane & 31;
    for (int k0 = 0; k0 < 256; k0 += BK) {
        #pragma unroll
        for (int q = 0; q < 8; ++q) {
            const f16* g = ((q & 1) ? g1 : g0) + k0 + (q >> 1) * 8;
            gload_lds16(g, ldsbase + q * 512);
        }
        __syncthreads();
        #pragma unroll
        for (int kk = 0; kk < 2; ++kk) {
            int k8 = kk * 2 + kh;
            f16x8 ah[2], al[2], bh[2], bl[2];
            #pragma unroll
            for (int i = 0; i < 2; ++i) {
                int m = wr * 64 + i * 32 + lm;
                ah[i] = *(const f16x8*)&LA[0][(k8 * 128 + m) * 8];
                al[i] = *(const f16x8*)&LA[1][(k8 * 128 + m) * 8];
                int nn = wc * 64 + i * 32 + lm;
                bh[i] = *(const f16x8*)&LB[0][(k8 * 128 + nn) * 8];
                bl[i] = *(const f16x8*)&LB[1][(k8 * 128 + nn) * 8];
            }
            #pragma unroll
            for (int i = 0; i < 2; ++i)
                #pragma unroll
                for (int jt = 0; jt < 2; ++jt) {
                    acc[i][jt] = __builtin_amdgcn_mfma_f32_32x32x16_f16(ah[i], bh[jt], acc[i][jt], 0, 0, 0);
                    acc[i][jt] = __builtin_amdgcn_mfma_f32_32x32x16_f16(ah[i], bl[jt], acc[i][jt], 0, 0, 0);
                    acc[i][jt] = __builtin_amdgcn_mfma_f32_32x32x16_f16(al[i], bh[jt], acc[i][jt], 0, 0, 0);
                }
        }
        __syncthreads();
    }

    #pragma unroll
    for (int jt = 0; jt < 2; ++jt) {
        int col = col0 + wc * 64 + jt * 32 + lm;
        float bv = bias[col];
        #pragma unroll
        for (int i = 0; i < 2; ++i) {
            #pragma unroll
            for (int r = 0; r < 16; ++r) {
                int row = row0 + wr * 64 + i * 32 + (r & 3) + 8 * (r >> 2) + 4 * kh;
                if (row < M) {
                    float v = acc[i][jt][r] + bv;
                    if (relu) v = fmaxf(v, 0.f);
                    f16 h = (f16)v;
                    size_t idx = (size_t)row * 256 + col;
                    Ohi[idx] = h; Olo[idx] = (f16)(v - (float)h);
                    if (Of32) Of32[idx] = v;
                }
            }
        }
    }
}

// ---------------- ctx GEMM: gather + masked resize GEMM + fused product ----------

__global__ __launch_bounds__(256) void ctx_gemm(
        const f16* __restrict__ fhi, const f16* __restrict__ flo,
        const int* __restrict__ perm, const int* __restrict__ plen,
        const int* __restrict__ label,
        const f16* __restrict__ Rhi, const f16* __restrict__ Rlo,
        const float* __restrict__ rbias, float* __restrict__ out,
        const f16* __restrict__ zp, int M) {
    __shared__ __align__(16) f16 LA[2][4096];
    __shared__ __align__(16) f16 LB[2][4096];
    __shared__ int s_perm[128], s_len[128], s_lbl[128];
    __shared__ int s_max;
    int tid = threadIdx.x, w = tid >> 6, lane = tid & 63;
    int row0 = (int)(gridDim.x - 1 - blockIdx.x) * BM;   // heavy (long-ctx) blocks first
    int col0 = blockIdx.y * BN;
    int wr = w >> 1, wc = w & 1;

    if (tid == 0) s_max = 0;
    if (tid < 128) {
        int r = row0 + tid;
        int p = (r < M) ? perm[r] : -1;
        s_perm[tid] = p;
        s_len[tid] = (r < M) ? plen[r] : 0;
    }
    __syncthreads();
    if (tid < 128) atomicMax(&s_max, s_len[tid]);
    __syncthreads();
    int maxlen = s_max;

    f32x16 acc[2][2] = {};
    f16* ldsbase = (w == 0) ? LA[0] : (w == 1) ? LA[1] : (w == 2) ? LB[0] : LB[1];
    const f16* srcF = (w == 0) ? fhi : flo;
    const f16* gB0 = zp; const f16* gB1 = zp;
    if (w >= 2) {
        const f16* s = (w == 2) ? Rhi : Rlo;
        gB0 = s + (size_t)(col0 + lane) * 2048;
        gB1 = s + (size_t)(col0 + 64 + lane) * 2048;
    }
    int kh = lane >> 5, lm = lane & 31;

    for (int j = 0; j < maxlen; ++j) {
        if (tid < 128) {
            int p = s_perm[tid];
            s_lbl[tid] = (p >= 0 && j < s_len[tid]) ? label[(size_t)p * 8 + j] : -1;
        }
        __syncthreads();
        const f16* gA0 = zp; const f16* gA1 = zp;
        if (w < 2) {
            int l0 = s_lbl[lane], l1 = s_lbl[64 + lane];
            gA0 = (l0 >= 0) ? srcF + (size_t)l0 * 256 : zp;
            gA1 = (l1 >= 0) ? srcF + (size_t)l1 * 256 : zp;
        }
        size_t jb = (size_t)j * 256;
        for (int k0 = 0; k0 < 256; k0 += BK) {
            #pragma unroll
            for (int q = 0; q < 8; ++q) {
                const f16* g;
                if (w < 2) g = ((q & 1) ? gA1 : gA0) + k0 + (q >> 1) * 8;
                else       g = ((q & 1) ? gB1 : gB0) + jb + k0 + (q >> 1) * 8;
                gload_lds16(g, ldsbase + q * 512);
            }
            __syncthreads();
            #pragma unroll
            for (int kk = 0; kk < 2; ++kk) {
                int k8 = kk * 2 + kh;
                f16x8 ah[2], al[2], bh[2], bl[2];
                #pragma unroll
                for (int i = 0; i < 2; ++i) {
                    int m = wr * 64 + i * 32 + lm;
                    ah[i] = *(const f16x8*)&LA[0][(k8 * 128 + m) * 8];
                    al[i] = *(const f16x8*)&LA[1][(k8 * 128 + m) * 8];
                    int nn = wc * 64 + i * 32 + lm;
                    bh[i] = *(const f16x8*)&LB[0][(k8 * 128 + nn) * 8];
                    bl[i] = *(const f16x8*)&LB[1][(k8 * 128 + nn) * 8];
                }
                #pragma unroll
                for (int i = 0; i < 2; ++i)
                    #pragma unroll
                    for (int jt = 0; jt < 2; ++jt) {
                        acc[i][jt] = __builtin_amdgcn_mfma_f32_32x32x16_f16(ah[i], bh[jt], acc[i][jt], 0, 0, 0);
                        acc[i][jt] = __builtin_amdgcn_mfma_f32_32x32x16_f16(ah[i], bl[jt], acc[i][jt], 0, 0, 0);
                        acc[i][jt] = __builtin_amdgcn_mfma_f32_32x32x16_f16(al[i], bh[jt], acc[i][jt], 0, 0, 0);
                    }
            }
            __syncthreads();
        }
    }

    #pragma unroll
    for (int jt = 0; jt < 2; ++jt) {
        int col = col0 + wc * 64 + jt * 32 + lm;
        float rbv = rbias[col];
        #pragma unroll
        for (int i = 0; i < 2; ++i) {
            #pragma unroll
            for (int r = 0; r < 16; ++r) {
                int lr = wr * 64 + i * 32 + (r & 3) + 8 * (r >> 2) + 4 * kh;
                int p = s_perm[lr];
                if (p >= 0) {
                    size_t idx = (size_t)p * 256 + col;
                    out[idx] = out[idx] * (acc[i][jt][r] + rbv);
                }
            }
        }
    }
}

// ---------------- launch ----------------

extern "C" void kernel_launch(void* const* d_in, const int* in_sizes, int n_in,
                              void* d_out, int out_size, void* d_ws, size_t ws_size,
                              hipStream_t stream) {
    const float* x    = (const float*)d_in[0];
    const int*   edge = (const int*)d_in[1];
    const int*   lbl  = (const int*)d_in[2];
    const int*   clen = (const int*)d_in[3];
    const float* gW   = (const float*)d_in[4];
    const float* gb   = (const float*)d_in[5];
    const float* rW   = (const float*)d_in[6];
    const float* rb   = (const float*)d_in[7];

    const int N = in_sizes[3];
    const int E = in_sizes[1] / 2;

    char* ws = (char*)d_ws;
    size_t off = 0;
    auto take = [&](size_t bytes) -> char* {
        char* p = ws + off;
        off = (off + bytes + 255) & ~(size_t)255;
        return p;
    };
    int*   cnt     = (int*)take((size_t)(2 * N + 16) * sizeof(int));
    int*   fillc   = cnt + N;
    int*   hist    = cnt + 2 * N;
    int*   row_ptr = (int*)take((size_t)(N + 1) * sizeof(int));
    int*   col_idx = (int*)take((size_t)E * sizeof(int));
    int*   perm    = (int*)take((size_t)N * sizeof(int));
    int*   plen    = (int*)take((size_t)N * sizeof(int));
    float* inv_s   = (float*)take((size_t)N * sizeof(float));
    f16*   zp      = (f16*)take(512);
    f16*   Wth     = (f16*)take((size_t)256 * 256 * sizeof(f16));
    f16*   Wtl     = (f16*)take((size_t)256 * 256 * sizeof(f16));
    f16*   Rth     = (f16*)take((size_t)256 * 2048 * sizeof(f16));
    f16*   Rtl     = (f16*)take((size_t)256 * 2048 * sizeof(f16));
    f16*   Ahi     = (f16*)take((size_t)N * 256 * sizeof(f16));
    f16*   Alo     = (f16*)take((size_t)N * 256 * sizeof(f16));
    f16*   Bhi     = (f16*)take((size_t)N * 256 * sizeof(f16));
    f16*   Blo     = (f16*)take((size_t)N * 256 * sizeof(f16));

    hipMemsetAsync(cnt, 0, (size_t)(2 * N + 16) * sizeof(int), stream);
    hipMemsetAsync(zp, 0, 512, stream);

    count_deg<<<(E + 255) / 256, 256, 0, stream>>>(edge + E, cnt, E);
    hist_len<<<(N + 255) / 256, 256, 0, stream>>>(clen, hist, N);
    scan_kernel<<<1, 1024, 0, stream>>>(cnt, row_ptr, inv_s, N, E);
    scan9<<<1, 64, 0, stream>>>(hist);
    fill_csr<<<(E + 255) / 256, 256, 0, stream>>>(edge, edge + E, row_ptr, fillc, col_idx, E);
    scatter_perm<<<(N + 255) / 256, 256, 0, stream>>>(clen, hist, perm, N);
    ctx_len_fill<<<(N + 255) / 256, 256, 0, stream>>>(clen, perm, plen, N);
    split_wt<<<256, 256, 0, stream>>>(gW, Wth, Wtl, 256);
    split_wt<<<2048, 256, 0, stream>>>(rW, Rth, Rtl, 2048);

    dim3 gg((N + BM - 1) / BM, 2);
    agg_f32<<<(N + 3) / 4, 256, 0, stream>>>(x, row_ptr, col_idx, inv_s, Ahi, Alo, N);
    gemm_pair<<<gg, 256, 0, stream>>>(Ahi, Alo, Wth, Wtl, gb, Bhi, Blo, nullptr, zp, N, 1);
    agg_pair<<<(N + 3) / 4, 256, 0, stream>>>(Bhi, Blo, row_ptr, col_idx, inv_s, Ahi, Alo, N);
    gemm_pair<<<gg, 256, 0, stream>>>(Ahi, Alo, Wth, Wtl, gb, Bhi, Blo, (float*)d_out, zp, N, 0);
    ctx_gemm<<<gg, 256, 0, stream>>>(Bhi, Blo, perm, plen, lbl, Rth, Rtl, rb, (float*)d_out, zp, N);
}

// Round 3
// 1278.259 us; speedup vs baseline: 1.0950x; 1.0561x over previous
//
#include <hip/hip_runtime.h>

typedef _Float16 f16;
typedef _Float16 f16x8 __attribute__((ext_vector_type(8)));
typedef float f32x16 __attribute__((ext_vector_type(16)));

#define BM 128
#define BN 128
#define BK 32

__device__ __forceinline__ void gload_lds16(const f16* g, f16* l) {
    __builtin_amdgcn_global_load_lds(
        (const __attribute__((address_space(1))) unsigned int*)g,
        (__attribute__((address_space(3))) unsigned int*)l, 16, 0, 0);
}

union H4 { f16 f[4]; ushort4 u; };

// ---------------- preprocessing (fused) ----------------

// grid covers E; also handles N-range work
__global__ void pre_count(const int* __restrict__ dst, const int* __restrict__ clen,
                          int* __restrict__ cnt, int* __restrict__ hist, int E, int n) {
    int i = blockIdx.x * blockDim.x + threadIdx.x;
    if (i < E) atomicAdd(&cnt[dst[i]], 1);
    if (i < n) { int l = clen[i]; if (l < 0) l = 0; if (l > 8) l = 8; atomicAdd(&hist[l], 1); }
}

__global__ __launch_bounds__(1024) void scan_all(const int* __restrict__ cnt,
                                                 int* __restrict__ row_ptr,
                                                 float* __restrict__ inv_s,
                                                 int* __restrict__ hist,
                                                 int n, int Etot) {
    __shared__ int sums[1024];
    int tid = threadIdx.x;
    if (tid == 0) {   // tiny 9-entry exclusive scan of the len histogram
        int run = 0;
        for (int i = 0; i < 9; ++i) { int c = hist[i]; hist[i] = run; run += c; }
    }
    int chunk = (n + 1023) / 1024;
    int start = tid * chunk;
    int end = start + chunk; if (end > n) end = n;
    int s = 0;
    for (int i = start; i < end; ++i) s += cnt[i];
    sums[tid] = s;
    __syncthreads();
    for (int off = 1; off < 1024; off <<= 1) {
        int v = (tid >= off) ? sums[tid - off] : 0;
        __syncthreads();
        sums[tid] += v;
        __syncthreads();
    }
    int base = (tid == 0) ? 0 : sums[tid - 1];
    for (int i = start; i < end; ++i) {
        row_ptr[i] = base;
        int c = cnt[i];
        inv_s[i] = rsqrtf((float)(c + 1));
        base += c;
    }
    if (tid == 0) row_ptr[n] = Etot;
}

// CSR fill (with fused edge weight) + context-length counting-sort scatter
__global__ void pre_fill(const int* __restrict__ src, const int* __restrict__ dst,
                         const int* __restrict__ row_ptr, int* __restrict__ fillc,
                         const float* __restrict__ inv_s, int2* __restrict__ ew,
                         const int* __restrict__ clen, int* __restrict__ hist,
                         int* __restrict__ perm, int E, int n) {
    int i = blockIdx.x * blockDim.x + threadIdx.x;
    if (i < E) {
        int d = dst[i];
        int s = src[i];
        int pos = row_ptr[d] + atomicAdd(&fillc[d], 1);
        ew[pos] = make_int2(s, __float_as_int(inv_s[s]));
    }
    if (i < n) {
        int l = clen[i]; if (l < 0) l = 0; if (l > 8) l = 8;
        int pos = atomicAdd(&hist[l], 1);
        perm[pos] = i;
    }
}

// weight splits (transposed) + permuted lengths. grid covers 2048*256.
__global__ void pre_misc(const float* __restrict__ gW, f16* __restrict__ Wth, f16* __restrict__ Wtl,
                         const float* __restrict__ rW, f16* __restrict__ Rth, f16* __restrict__ Rtl,
                         const int* __restrict__ clen, const int* __restrict__ perm,
                         int* __restrict__ plen, int n) {
    int idx = blockIdx.x * blockDim.x + threadIdx.x;
    if (idx < 256 * 256) {           // gcn_W: [256][256] -> th/tl [n][k]
        int nrow = idx >> 8, k = idx & 255;
        float v = gW[(size_t)k * 256 + nrow];
        f16 h = (f16)v; Wth[idx] = h; Wtl[idx] = (f16)(v - (float)h);
    }
    if (idx < 2048 * 256) {          // resize_W: [2048][256] -> th/tl [256][2048]
        int nrow = idx >> 11, k = idx & 2047;
        float v = rW[(size_t)k * 256 + nrow];
        f16 h = (f16)v; Rth[idx] = h; Rtl[idx] = (f16)(v - (float)h);
    }
    if (idx < n) {
        int l = clen[perm[idx]]; if (l < 0) l = 0; if (l > 8) l = 8;
        plen[idx] = l;
    }
}

// ---------------- aggregation: out_pair = split( s_i*(s_i*x_i + sum w_e * x_src) ) ----

__global__ __launch_bounds__(256) void agg_split(const float* __restrict__ X,
        const int2* __restrict__ ew, const int* __restrict__ rp,
        const float* __restrict__ invs, f16* __restrict__ ohi, f16* __restrict__ olo, int n) {
    int wv = threadIdx.x >> 6, lane = threadIdx.x & 63;
    int node = blockIdx.x * 4 + wv; if (node >= n) return;
    float si = invs[node];
    const float4* selfr = (const float4*)(X + (size_t)node * 256) + lane;
    float4 a = *selfr;
    float4 acc = make_float4(a.x * si, a.y * si, a.z * si, a.w * si);
    int e0 = rp[node], e1 = rp[node + 1];
    int e = e0;
    for (; e + 4 <= e1; e += 4) {
        int2 q0 = ew[e], q1 = ew[e + 1], q2 = ew[e + 2], q3 = ew[e + 3];
        float4 v0 = *((const float4*)(X + (size_t)q0.x * 256) + lane);
        float4 v1 = *((const float4*)(X + (size_t)q1.x * 256) + lane);
        float4 v2 = *((const float4*)(X + (size_t)q2.x * 256) + lane);
        float4 v3 = *((const float4*)(X + (size_t)q3.x * 256) + lane);
        float w0 = __int_as_float(q0.y), w1 = __int_as_float(q1.y);
        float w2 = __int_as_float(q2.y), w3 = __int_as_float(q3.y);
        acc.x = fmaf(w0, v0.x, acc.x); acc.y = fmaf(w0, v0.y, acc.y);
        acc.z = fmaf(w0, v0.z, acc.z); acc.w = fmaf(w0, v0.w, acc.w);
        acc.x = fmaf(w1, v1.x, acc.x); acc.y = fmaf(w1, v1.y, acc.y);
        acc.z = fmaf(w1, v1.z, acc.z); acc.w = fmaf(w1, v1.w, acc.w);
        acc.x = fmaf(w2, v2.x, acc.x); acc.y = fmaf(w2, v2.y, acc.y);
        acc.z = fmaf(w2, v2.z, acc.z); acc.w = fmaf(w2, v2.w, acc.w);
        acc.x = fmaf(w3, v3.x, acc.x); acc.y = fmaf(w3, v3.y, acc.y);
        acc.z = fmaf(w3, v3.z, acc.z); acc.w = fmaf(w3, v3.w, acc.w);
    }
    for (; e < e1; ++e) {
        int2 q = ew[e];
        float4 v = *((const float4*)(X + (size_t)q.x * 256) + lane);
        float w = __int_as_float(q.y);
        acc.x = fmaf(w, v.x, acc.x); acc.y = fmaf(w, v.y, acc.y);
        acc.z = fmaf(w, v.z, acc.z); acc.w = fmaf(w, v.w, acc.w);
    }
    float o[4] = {si * acc.x, si * acc.y, si * acc.z, si * acc.w};
    H4 hh, ll;
    #pragma unroll
    for (int k = 0; k < 4; ++k) { f16 h = (f16)o[k]; hh.f[k] = h; ll.f[k] = (f16)(o[k] - (float)h); }
    size_t off = (size_t)node * 256 + lane * 4;
    *(ushort4*)(ohi + off) = hh.u;
    *(ushort4*)(olo + off) = ll.u;
}

// ---------------- split-f16 MFMA GEMM: Of32 = A@W + b (relu opt); optional hi/lo split out

__global__ __launch_bounds__(256) void gemm_pair(
        const f16* __restrict__ Ahi, const f16* __restrict__ Alo,
        const f16* __restrict__ Bhi, const f16* __restrict__ Blo,
        const float* __restrict__ bias,
        float* __restrict__ Of32, f16* __restrict__ Ohi, f16* __restrict__ Olo,
        const f16* __restrict__ zp, int M, int relu) {
    __shared__ __align__(16) f16 LA[2][4096];
    __shared__ __align__(16) f16 LB[2][4096];
    int tid = threadIdx.x, w = tid >> 6, lane = tid & 63;
    int row0 = blockIdx.x * BM, col0 = blockIdx.y * BN;
    int wr = w >> 1, wc = w & 1;
    f32x16 acc[2][2] = {};

    const f16* g0; const f16* g1;
    f16* ldsbase = (w == 0) ? LA[0] : (w == 1) ? LA[1] : (w == 2) ? LB[0] : LB[1];
    if (w < 2) {
        const f16* s = (w == 0) ? Ahi : Alo;
        int r0v = row0 + lane, r1v = row0 + 64 + lane;
        g0 = (r0v < M) ? s + (size_t)r0v * 256 : zp;
        g1 = (r1v < M) ? s + (size_t)r1v * 256 : zp;
    } else {
        const f16* s = (w == 2) ? Bhi : Blo;
        g0 = s + (size_t)(col0 + lane) * 256;
        g1 = s + (size_t)(col0 + 64 + lane) * 256;
    }

    int kh = lane >> 5, lm = lane & 31;
    for (int k0 = 0; k0 < 256; k0 += BK) {
        #pragma unroll
        for (int q = 0; q < 8; ++q) {
            const f16* g = ((q & 1) ? g1 : g0) + k0 + (q >> 1) * 8;
            gload_lds16(g, ldsbase + q * 512);
        }
        __syncthreads();
        #pragma unroll
        for (int kk = 0; kk < 2; ++kk) {
            int k8 = kk * 2 + kh;
            f16x8 ah[2], al[2], bh[2], bl[2];
            #pragma unroll
            for (int i = 0; i < 2; ++i) {
                int m = wr * 64 + i * 32 + lm;
                ah[i] = *(const f16x8*)&LA[0][(k8 * 128 + m) * 8];
                al[i] = *(const f16x8*)&LA[1][(k8 * 128 + m) * 8];
                int nn = wc * 64 + i * 32 + lm;
                bh[i] = *(const f16x8*)&LB[0][(k8 * 128 + nn) * 8];
                bl[i] = *(const f16x8*)&LB[1][(k8 * 128 + nn) * 8];
            }
            #pragma unroll
            for (int i = 0; i < 2; ++i)
                #pragma unroll
                for (int jt = 0; jt < 2; ++jt) {
                    acc[i][jt] = __builtin_amdgcn_mfma_f32_32x32x16_f16(ah[i], bh[jt], acc[i][jt], 0, 0, 0);
                    acc[i][jt] = __builtin_amdgcn_mfma_f32_32x32x16_f16(ah[i], bl[jt], acc[i][jt], 0, 0, 0);
                    acc[i][jt] = __builtin_amdgcn_mfma_f32_32x32x16_f16(al[i], bh[jt], acc[i][jt], 0, 0, 0);
                }
        }
        __syncthreads();
    }

    #pragma unroll
    for (int jt = 0; jt < 2; ++jt) {
        int col = col0 + wc * 64 + jt * 32 + lm;
        float bv = bias[col];
        #pragma unroll
        for (int i = 0; i < 2; ++i) {
            #pragma unroll
            for (int r = 0; r < 16; ++r) {
                int row = row0 + wr * 64 + i * 32 + (r & 3) + 8 * (r >> 2) + 4 * kh;
                if (row < M) {
                    float v = acc[i][jt][r] + bv;
                    if (relu) v = fmaxf(v, 0.f);
                    size_t idx = (size_t)row * 256 + col;
                    Of32[idx] = v;
                    if (Ohi) {
                        f16 h = (f16)v;
                        Ohi[idx] = h; Olo[idx] = (f16)(v - (float)h);
                    }
                }
            }
        }
    }
}

// ---------------- ctx GEMM: BM=128 x BN=256, 512 threads, single col-block ---------
// out[p,:] = feat2[p,:] * ( sum_{j<len_p} feat2hi/lo[label[p,j],:] @ R[j] + rb )

__global__ __launch_bounds__(512) void ctx_gemm(
        const f16* __restrict__ fhi, const f16* __restrict__ flo,
        const int* __restrict__ perm, const int* __restrict__ plen,
        const int* __restrict__ label,
        const f16* __restrict__ Rhi, const f16* __restrict__ Rlo,
        const float* __restrict__ rbias,
        const float* __restrict__ feat2, float* __restrict__ out,
        const f16* __restrict__ zp, int M) {
    // LDS slab: A-hi[4096] | A-lo[4096] | B-hi[8192] | B-lo[8192]  (f16 units) = 48KB
    __shared__ __align__(16) f16 LDS[24576];
    __shared__ int s_lbl[8][128];
    __shared__ int s_perm[128];
    __shared__ int s_max;
    int tid = threadIdx.x, w = tid >> 6, lane = tid & 63;
    int row0 = (int)(gridDim.x - 1 - blockIdx.x) * BM;   // longest-context blocks first
    int wr = w >> 2, wc = w & 3;
    int kh = lane >> 5, lm = lane & 31;

    if (tid == 0) s_max = 0;
    __syncthreads();
    if (tid < 128) {
        int r = row0 + tid;
        int p = (r < M) ? perm[r] : -1;
        s_perm[tid] = p;
        int len = (r < M) ? plen[r] : 0;
        atomicMax(&s_max, len);
        int4 l0 = make_int4(-1, -1, -1, -1), l1 = l0;
        if (p >= 0) {
            l0 = *(const int4*)(label + (size_t)p * 8);
            l1 = *(const int4*)(label + (size_t)p * 8 + 4);
        }
        s_lbl[0][tid] = (0 < len) ? l0.x : -1;
        s_lbl[1][tid] = (1 < len) ? l0.y : -1;
        s_lbl[2][tid] = (2 < len) ? l0.z : -1;
        s_lbl[3][tid] = (3 < len) ? l0.w : -1;
        s_lbl[4][tid] = (4 < len) ? l1.x : -1;
        s_lbl[5][tid] = (5 < len) ? l1.y : -1;
        s_lbl[6][tid] = (6 < len) ? l1.z : -1;
        s_lbl[7][tid] = (7 < len) ? l1.w : -1;
    }
    __syncthreads();
    int T = s_max * 8;    // slabs: (j, k0) pairs

    f32x16 acc[2][2] = {};

    for (int t = 0; t < T; ++t) {
        int j = t >> 3, k0 = (t & 7) * 32;
        // ---- stage slab t ----
        if (w < 4) {
            const f16* srcF = (w < 2) ? fhi : flo;
            f16* abase = &LDS[(w < 2) ? 0 : 4096];
            int rl = ((w & 1) << 6) + lane;
            int lbl = s_lbl[j][rl];
            const f16* g = (lbl >= 0) ? srcF + (size_t)lbl * 256 + k0 : zp;
            #pragma unroll
            for (int k8 = 0; k8 < 4; ++k8)
                gload_lds16(g + k8 * 8, abase + (k8 * 128 + ((w & 1) << 6)) * 8);
        } else {
            const f16* srcR = (w < 6) ? Rhi : Rlo;
            f16* bbase = &LDS[8192 + ((w < 6) ? 0 : 8192)];
            int ch = w & 1;
            const f16* gb = srcR + (size_t)(ch * 128 + lane) * 2048 + (size_t)j * 256 + k0;
            #pragma unroll
            for (int k8 = 0; k8 < 4; ++k8)
                #pragma unroll
                for (int c2 = 0; c2 < 2; ++c2)
                    gload_lds16(gb + (size_t)c2 * 64 * 2048 + k8 * 8,
                                bbase + (k8 * 256 + ch * 128 + c2 * 64) * 8);
        }
        __syncthreads();
        // ---- compute slab t ----
        #pragma unroll
        for (int kk = 0; kk < 2; ++kk) {
            int k8 = kk * 2 + kh;
            f16x8 ah[2], al[2], bh[2], bl[2];
            #pragma unroll
            for (int i = 0; i < 2; ++i) {
                int m = wr * 64 + i * 32 + lm;
                ah[i] = *(const f16x8*)&LDS[(k8 * 128 + m) * 8];
                al[i] = *(const f16x8*)&LDS[4096 + (k8 * 128 + m) * 8];
                int nn = wc * 64 + i * 32 + lm;
                bh[i] = *(const f16x8*)&LDS[8192 + (k8 * 256 + nn) * 8];
                bl[i] = *(const f16x8*)&LDS[16384 + (k8 * 256 + nn) * 8];
            }
            #pragma unroll
            for (int i = 0; i < 2; ++i)
                #pragma unroll
                for (int jt = 0; jt < 2; ++jt) {
                    acc[i][jt] = __builtin_amdgcn_mfma_f32_32x32x16_f16(ah[i], bh[jt], acc[i][jt], 0, 0, 0);
                    acc[i][jt] = __builtin_amdgcn_mfma_f32_32x32x16_f16(ah[i], bl[jt], acc[i][jt], 0, 0, 0);
                    acc[i][jt] = __builtin_amdgcn_mfma_f32_32x32x16_f16(al[i], bh[jt], acc[i][jt], 0, 0, 0);
                }
        }
        __syncthreads();
    }

    #pragma unroll
    for (int jt = 0; jt < 2; ++jt) {
        int col = wc * 64 + jt * 32 + lm;
        float rbv = rbias[col];
        #pragma unroll
        for (int i = 0; i < 2; ++i) {
            #pragma unroll
            for (int r = 0; r < 16; ++r) {
                int lr = wr * 64 + i * 32 + (r & 3) + 8 * (r >> 2) + 4 * kh;
                int p = s_perm[lr];
                if (p >= 0) {
                    size_t idx = (size_t)p * 256 + col;
                    out[idx] = feat2[idx] * (acc[i][jt][r] + rbv);
                }
            }
        }
    }
}

// ---------------- launch ----------------

extern "C" void kernel_launch(void* const* d_in, const int* in_sizes, int n_in,
                              void* d_out, int out_size, void* d_ws, size_t ws_size,
                              hipStream_t stream) {
    const float* x    = (const float*)d_in[0];
    const int*   edge = (const int*)d_in[1];
    const int*   lbl  = (const int*)d_in[2];
    const int*   clen = (const int*)d_in[3];
    const float* gW   = (const float*)d_in[4];
    const float* gb   = (const float*)d_in[5];
    const float* rW   = (const float*)d_in[6];
    const float* rb   = (const float*)d_in[7];

    const int N = in_sizes[3];
    const int E = in_sizes[1] / 2;

    char* ws = (char*)d_ws;
    size_t off = 0;
    auto take = [&](size_t bytes) -> char* {
        char* p = ws + off;
        off = (off + bytes + 255) & ~(size_t)255;
        return p;
    };
    int*   cnt     = (int*)take((size_t)(2 * N + 16) * sizeof(int));
    int*   fillc   = cnt + N;
    int*   hist    = cnt + 2 * N;
    int*   row_ptr = (int*)take((size_t)(N + 1) * sizeof(int));
    int2*  ew      = (int2*)take((size_t)E * sizeof(int2));
    int*   perm    = (int*)take((size_t)N * sizeof(int));
    int*   plen    = (int*)take((size_t)N * sizeof(int));
    float* inv_s   = (float*)take((size_t)N * sizeof(float));
    f16*   zp      = (f16*)take(512);
    f16*   Wth     = (f16*)take((size_t)256 * 256 * sizeof(f16));
    f16*   Wtl     = (f16*)take((size_t)256 * 256 * sizeof(f16));
    f16*   Rth     = (f16*)take((size_t)256 * 2048 * sizeof(f16));
    f16*   Rtl     = (f16*)take((size_t)256 * 2048 * sizeof(f16));
    f16*   Ahi     = (f16*)take((size_t)N * 256 * sizeof(f16));
    f16*   Alo     = (f16*)take((size_t)N * 256 * sizeof(f16));
    float* Y1      = (float*)take((size_t)N * 256 * sizeof(float));
    float* feat2   = (float*)take((size_t)N * 256 * sizeof(float));
    f16*   Fhi     = (f16*)take((size_t)N * 256 * sizeof(f16));
    f16*   Flo     = (f16*)take((size_t)N * 256 * sizeof(f16));

    hipMemsetAsync(cnt, 0, (size_t)(2 * N + 16) * sizeof(int), stream);
    hipMemsetAsync(zp, 0, 512, stream);

    int gE = (E + 255) / 256;
    pre_count<<<gE, 256, 0, stream>>>(edge + E, clen, cnt, hist, E, N);
    scan_all<<<1, 1024, 0, stream>>>(cnt, row_ptr, inv_s, hist, N, E);
    pre_fill<<<gE, 256, 0, stream>>>(edge, edge + E, row_ptr, fillc, inv_s, ew,
                                     clen, hist, perm, E, N);
    pre_misc<<<2048, 256, 0, stream>>>(gW, Wth, Wtl, rW, Rth, Rtl, clen, perm, plen, N);

    dim3 gg((N + BM - 1) / BM, 2);
    agg_split<<<(N + 3) / 4, 256, 0, stream>>>(x, ew, row_ptr, inv_s, Ahi, Alo, N);
    gemm_pair<<<gg, 256, 0, stream>>>(Ahi, Alo, Wth, Wtl, gb, Y1, nullptr, nullptr, zp, N, 1);
    agg_split<<<(N + 3) / 4, 256, 0, stream>>>(Y1, ew, row_ptr, inv_s, Ahi, Alo, N);
    gemm_pair<<<gg, 256, 0, stream>>>(Ahi, Alo, Wth, Wtl, gb, feat2, Fhi, Flo, zp, N, 0);
    ctx_gemm<<<(N + BM - 1) / BM, 512, 0, stream>>>(Fhi, Flo, perm, plen, lbl, Rth, Rtl,
                                                    rb, feat2, (float*)d_out, zp, N);
}